// Round 11
// baseline (99.689 us; speedup 1.0000x reference)
//
#include <hip/hip_runtime.h>

typedef unsigned short u16;
typedef unsigned int u32;
typedef unsigned long long u64;
typedef __attribute__((ext_vector_type(8))) __bf16 bf16x8;
typedef __attribute__((ext_vector_type(4))) float f32x4;
typedef __attribute__((ext_vector_type(4))) int i32x4;

#define MFMA16(a, b, c) __builtin_amdgcn_mfma_f32_16x16x32_bf16(a, b, c, 0, 0, 0)

__device__ __forceinline__ u16 f2b(float f) {
  __bf16 h = (__bf16)f;
  return __builtin_bit_cast(u16, h);
}

__device__ __forceinline__ float mx3(float a, float b, float c) {
  return fmaxf(fmaxf(a, b), c);  // clang fuses to v_max3_f32
}

// global -> LDS direct (wave-uniform LDS base + lane*16; global addr per-lane)
__device__ __forceinline__ void gl_lds16(const void* g, void* l) {
  __builtin_amdgcn_global_load_lds(
      (const __attribute__((address_space(1))) void*)g,
      (__attribute__((address_space(3))) void*)l, 16, 0, 0);
}

__device__ __forceinline__ bf16x8 ldf(const void* p) {
  return __builtin_bit_cast(bf16x8, *(const i32x4*)p);
}

// ---------------- fused f32 -> bf16 convert (one launch) ----------------
__global__ __launch_bounds__(256) void cvt3_kernel(
    const float4* __restrict__ a, ushort4* __restrict__ oa, int na4,
    const float4* __restrict__ b, ushort4* __restrict__ ob, int nb4,
    const float4* __restrict__ c, ushort4* __restrict__ oc, int nc4) {
  const int step = gridDim.x * blockDim.x;
  const int t0 = blockIdx.x * blockDim.x + threadIdx.x;
  for (int i = t0; i < na4; i += step) {
    float4 v = a[i];
    ushort4 o; o.x = f2b(v.x); o.y = f2b(v.y); o.z = f2b(v.z); o.w = f2b(v.w);
    oa[i] = o;
  }
  for (int i = t0; i < nb4; i += step) {
    float4 v = b[i];
    ushort4 o; o.x = f2b(v.x); o.y = f2b(v.y); o.z = f2b(v.z); o.w = f2b(v.w);
    ob[i] = o;
  }
  for (int i = t0; i < nc4; i += step) {
    float4 v = c[i];
    ushort4 o; o.x = f2b(v.x); o.y = f2b(v.y); o.z = f2b(v.z); o.w = f2b(v.w);
    oc[i] = o;
  }
}

// ---------------- GEMM v4 (unchanged from round 8) ----------------
template <int BM, int EPI>
__global__ __launch_bounds__(256, 3) void gemm4(
    const u16* __restrict__ A, const u16* __restrict__ B,
    const float* __restrict__ bias, int M, int N, int K,
    u16* __restrict__ q_s, u16* __restrict__ k_s, u16* __restrict__ vt_s,
    float* __restrict__ outf) {
  constexpr int BN = 192;
  constexpr int MR = BM / 32;
  constexpr int NR = 6;
  constexpr int IA = BM / 32;
  constexpr int IB = 6;
  __shared__ __align__(16) u16 As[BM * 64];
  __shared__ __align__(16) u16 Bs[BN * 64];
  const int tid = threadIdx.x;
  const int w = tid >> 6, l = tid & 63;
  const int lo = l & 15, hi = l >> 4;
  const int wr = w >> 1, wc = w & 1;
  const int nwg = gridDim.x * gridDim.y;
  int bid = blockIdx.y * gridDim.x + blockIdx.x;
  bid = (bid & 7) * (nwg >> 3) + (bid >> 3);
  const int bm0 = (bid / gridDim.x) * BM;
  const int bn0 = (bid % gridDim.x) * BN;
  const size_t Kb = (size_t)K * 2;
  const char* Ab = (const char*)A;
  const char* Bb = (const char*)B;
  const int lrow8 = l >> 3;
  const int lcol = (l & 7) * 16;

  f32x4 acc[MR][NR] = {};

  for (int kt = 0; kt < K; kt += 64) {
    __syncthreads();
#pragma unroll
    for (int i = 0; i < IA; ++i) {
      int rl = (w * IA + i) * 8 + lrow8;
      int cb = lcol ^ ((rl & 7) << 4);
      gl_lds16(Ab + (size_t)(bm0 + rl) * Kb + kt * 2 + cb,
               (char*)As + (w * IA + i) * 1024);
    }
#pragma unroll
    for (int i = 0; i < IB; ++i) {
      int rl = (w * IB + i) * 8 + lrow8;
      int cb = lcol ^ ((rl & 7) << 4);
      gl_lds16(Bb + (size_t)(bn0 + rl) * Kb + kt * 2 + cb,
               (char*)Bs + (w * IB + i) * 1024);
    }
    __syncthreads();
#pragma unroll
    for (int ks = 0; ks < 2; ++ks) {
      bf16x8 bfr[NR];
#pragma unroll
      for (int nf = 0; nf < NR; ++nf) {
        int r = wc * 96 + nf * 16 + lo;
        bfr[nf] = ldf((char*)Bs + r * 128 + ((ks * 64 + hi * 16) ^ ((r & 7) << 4)));
      }
#pragma unroll
      for (int mf = 0; mf < MR; ++mf) {
        int r = wr * (MR * 16) + mf * 16 + lo;
        bf16x8 afr = ldf((char*)As + r * 128 + ((ks * 64 + hi * 16) ^ ((r & 7) << 4)));
#pragma unroll
        for (int nf = 0; nf < NR; ++nf) acc[mf][nf] = MFMA16(afr, bfr[nf], acc[mf][nf]);
      }
    }
  }

#pragma unroll
  for (int nf = 0; nf < NR; ++nf) {
    int col = bn0 + wc * 96 + nf * 16 + lo;
    float bv = bias[col];
    if (EPI == 0) {
      int seg = col / 768;
      int cs = col - seg * 768;
      int h = cs >> 6, d = cs & 63;
      u16* dst = (seg == 0) ? q_s : k_s;
#pragma unroll
      for (int mf = 0; mf < MR; ++mf) {
        int m0 = bm0 + wr * (MR * 16) + mf * 16 + hi * 4;
        int bb = m0 >> 10, t0 = m0 & 1023;
        size_t bh = (size_t)(bb * 12 + h);
        if (seg < 2) {
#pragma unroll
          for (int r = 0; r < 4; ++r)
            dst[(bh * 1024 + t0 + r) * 64 + d] = f2b(acc[mf][nf][r] + bv);
        } else {
          ushort4 pk;
          pk.x = f2b(acc[mf][nf][0] + bv);
          pk.y = f2b(acc[mf][nf][1] + bv);
          pk.z = f2b(acc[mf][nf][2] + bv);
          pk.w = f2b(acc[mf][nf][3] + bv);
          *(ushort4*)&vt_s[(bh * 64 + d) * 1024 + t0] = pk;
        }
      }
    } else {
#pragma unroll
      for (int mf = 0; mf < MR; ++mf) {
        int m0 = bm0 + wr * (MR * 16) + mf * 16 + hi * 4;
#pragma unroll
        for (int r = 0; r < 4; ++r) outf[(size_t)(m0 + r) * N + col] = acc[mf][nf][r] + bv;
      }
    }
  }
}

// ---------------- causal flash attention, v8: dual-strip merged ----------------
// v7's iter structure (dbuf K/V, 2 barriers, packed P via Ps, swapped QK^T),
// but the tile pair {pr, 15-pr} runs in ONE pass: loop kt = 0..15-pr; strip B
// (tile 15-pr) always active, strip A (tile pr) active while kt <= pr. K-frag
// ds_reads and V-frags are loaded ONCE per iter and feed both strips' MFMAs:
// staged bytes -26%, barriers -26%, K/V ds_reads -19% vs v7; exp/MFMA totals
// unchanged. fmax reductions shaped for v_max3 (T17). VGPR ~150 <= 170
// (3 waves/SIMD = the grid-limited occupancy; launch_bounds(256,3)).
__global__ __launch_bounds__(256, 3) void attn_kernel(
    const u16* __restrict__ Q, const u16* __restrict__ Kg,
    const u16* __restrict__ Vt, u16* __restrict__ Y) {
  __shared__ __align__(16) u16 Ks[2][64 * 64];
  __shared__ __align__(16) u16 Vs[2][64 * 64];
  __shared__ __align__(16) u16 Ps[4][16 * 64];
  const int tid = threadIdx.x;
  const int w = tid >> 6, l = tid & 63;
  const int lo = l & 15, hi = l >> 4;
  // XCD-aware bijective remap (768 blocks % 8 == 0)
  int bid = blockIdx.y * gridDim.x + blockIdx.x;
  bid = (bid & 7) * 96 + (bid >> 3);
  const int bh = bid >> 3;
  const int pr = bid & 7;  // tiles {pr, 15-pr}
  const int b = bh / 12, h = bh % 12;
  const float c1 = 0.125f * 1.44269504f;  // scale * log2(e)
  char* pw = (char*)&Ps[w][0];
  const int swl = (lo & 7) << 4;
  const u16* Qb = Q + (size_t)bh * 65536;
  const char* Kbp = (const char*)(Kg + (size_t)bh * 65536);
  const char* Vbp = (const char*)(Vt + (size_t)bh * 65536);  // [64 d][1024 t]

  bf16x8 onesv;
#pragma unroll
  for (int j = 0; j < 8; ++j) onesv[j] = (__bf16)1.0f;

  auto STAGE = [&](int buf, int kb) {
#pragma unroll
    for (int i = 0; i < 2; ++i) {
      int c = w * 2 + i;
      int row = c * 8 + (l >> 3);                    // 8 rows (128B) / chunk
      int cb = ((l & 7) * 16) ^ ((row & 7) << 4);    // inverse-swizzled source
      gl_lds16(Kbp + (size_t)(kb + row) * 128 + cb, (char*)&Ks[buf][0] + c * 1024);
      gl_lds16(Vbp + (size_t)row * 2048 + (size_t)kb * 2 + cb, (char*)&Vs[buf][0] + c * 1024);
    }
  };

  const int q0A = pr * 64 + w * 16;
  const int q0B = (15 - pr) * 64 + w * 16;
  const int ntA = pr + 1;   // strip A KV tiles
  const int nt = 16 - pr;   // total loop iters (strip B KV tiles)
  const int qrA = q0A + lo;
  const int qrB = q0B + lo;

  bf16x8 qfA[2], qfB[2];
#pragma unroll
  for (int ks = 0; ks < 2; ++ks) {
    qfA[ks] = ldf(Qb + (size_t)(q0A + lo) * 64 + ks * 32 + hi * 8);
    qfB[ks] = ldf(Qb + (size_t)(q0B + lo) * 64 + ks * 32 + hi * 8);
  }

  f32x4 oA[4] = {}, oB[4] = {};
  f32x4 lsA = {0.f, 0.f, 0.f, 0.f}, lsB = {0.f, 0.f, 0.f, 0.f};
  float mA = -1e30f, mB = -1e30f;

  STAGE(0, 0);
  for (int kt = 0; kt < nt; ++kt) {
    const int cur = kt & 1;
    if (kt + 1 < nt) {
      STAGE(cur ^ 1, (kt + 1) * 64);
      asm volatile("s_waitcnt vmcnt(4)" ::: "memory");  // stage(kt) landed
    } else {
      asm volatile("s_waitcnt vmcnt(0)" ::: "memory");
    }
    __builtin_amdgcn_s_barrier();
    __builtin_amdgcn_sched_barrier(0);
    const char* Kt = (const char*)&Ks[cur][0];
    const char* Vv = (const char*)&Vs[cur][0];
    const int kb = kt * 64;
    const bool actA = kt < ntA;

    // ---- swapped QK^T for both strips, K-frags read ONCE
    f32x4 sA[4] = {}, sB[4] = {};
    __builtin_amdgcn_s_setprio(1);
#pragma unroll
    for (int kf = 0; kf < 4; ++kf) {
      int rb = (kf * 16 + lo) * 128;
#pragma unroll
      for (int ks = 0; ks < 2; ++ks) {
        bf16x8 kk = ldf(Kt + rb + ((ks * 64 + hi * 16) ^ swl));
        sB[kf] = MFMA16(kk, qfB[ks], sB[kf]);
        if (actA) sA[kf] = MFMA16(kk, qfA[ks], sA[kf]);
      }
    }
    __builtin_amdgcn_s_setprio(0);
    // ---- V frags read ONCE (shared by both strips' PV)
    bf16x8 vb[4][2];
#pragma unroll
    for (int nd = 0; nd < 4; ++nd) {
      int rb = (nd * 16 + lo) * 128;
#pragma unroll
      for (int ks = 0; ks < 2; ++ks)
        vb[nd][ks] = ldf(Vv + rb + ((ks * 64 + hi * 16) ^ swl));
    }
    // ---- causal masks (diag tiles only)
    if (kt == nt - 1) {  // strip B diagonal
#pragma unroll
      for (int kf = 0; kf < 4; ++kf)
#pragma unroll
        for (int r = 0; r < 4; ++r)
          if (kb + kf * 16 + hi * 4 + r > qrB) sB[kf][r] = -1e30f;
    }
    if (actA && kt == ntA - 1) {  // strip A diagonal
#pragma unroll
      for (int kf = 0; kf < 4; ++kf)
#pragma unroll
        for (int r = 0; r < 4; ++r)
          if (kb + kf * 16 + hi * 4 + r > qrA) sA[kf][r] = -1e30f;
    }

    // ================= strip B: softmax + P + PV =================
    {
      float t0 = mx3(sB[0][0], sB[0][1], sB[0][2]);
      float t1 = mx3(sB[0][3], sB[1][0], sB[1][1]);
      float t2 = mx3(sB[1][2], sB[1][3], sB[2][0]);
      float t3 = mx3(sB[2][1], sB[2][2], sB[2][3]);
      float t4 = mx3(sB[3][0], sB[3][1], sB[3][2]);
      float lm = fmaxf(mx3(t0, t1, t2), mx3(t3, t4, sB[3][3]));
      if (__any(lm * c1 > mB + 8.0f)) {  // defer-max (T13)
        float LM = fmaxf(lm, __shfl_xor(lm, 16));
        LM = fmaxf(LM, __shfl_xor(LM, 32));
        float Mn = fmaxf(mB, LM * c1);
        float alP = __builtin_amdgcn_exp2f(mB - Mn);
        mB = Mn;
        f32x4 alo;
#pragma unroll
        for (int r = 0; r < 4; ++r) alo[r] = __shfl(alP, hi * 4 + r);
#pragma unroll
        for (int nd = 0; nd < 4; ++nd)
#pragma unroll
          for (int r = 0; r < 4; ++r) oB[nd][r] *= alo[r];
#pragma unroll
        for (int r = 0; r < 4; ++r) lsB[r] *= alo[r];
      }
#pragma unroll
      for (int kf = 0; kf < 4; ++kf)
#pragma unroll
        for (int r = 0; r < 4; ++r)
          sB[kf][r] = __builtin_amdgcn_exp2f(fmaf(sB[kf][r], c1, -mB));
#pragma unroll
      for (int kf = 0; kf < 4; ++kf) {
        u32 w0 = (u32)f2b(sB[kf][0]) | ((u32)f2b(sB[kf][1]) << 16);
        u32 w1 = (u32)f2b(sB[kf][2]) | ((u32)f2b(sB[kf][3]) << 16);
        *(u64*)(pw + lo * 128 + ((kf * 32 + hi * 8) ^ swl)) = (u64)w0 | ((u64)w1 << 32);
      }
      bf16x8 pa[2];
#pragma unroll
      for (int ks = 0; ks < 2; ++ks)
        pa[ks] = ldf(pw + lo * 128 + ((ks * 64 + hi * 16) ^ swl));
      __builtin_amdgcn_s_setprio(1);
#pragma unroll
      for (int ks = 0; ks < 2; ++ks) {
#pragma unroll
        for (int nd = 0; nd < 4; ++nd) oB[nd] = MFMA16(pa[ks], vb[nd][ks], oB[nd]);
        lsB = MFMA16(pa[ks], onesv, lsB);
      }
      __builtin_amdgcn_s_setprio(0);
    }

    // ================= strip A (active iters only) =================
    if (actA) {
      float t0 = mx3(sA[0][0], sA[0][1], sA[0][2]);
      float t1 = mx3(sA[0][3], sA[1][0], sA[1][1]);
      float t2 = mx3(sA[1][2], sA[1][3], sA[2][0]);
      float t3 = mx3(sA[2][1], sA[2][2], sA[2][3]);
      float t4 = mx3(sA[3][0], sA[3][1], sA[3][2]);
      float lm = fmaxf(mx3(t0, t1, t2), mx3(t3, t4, sA[3][3]));
      if (__any(lm * c1 > mA + 8.0f)) {
        float LM = fmaxf(lm, __shfl_xor(lm, 16));
        LM = fmaxf(LM, __shfl_xor(LM, 32));
        float Mn = fmaxf(mA, LM * c1);
        float alP = __builtin_amdgcn_exp2f(mA - Mn);
        mA = Mn;
        f32x4 alo;
#pragma unroll
        for (int r = 0; r < 4; ++r) alo[r] = __shfl(alP, hi * 4 + r);
#pragma unroll
        for (int nd = 0; nd < 4; ++nd)
#pragma unroll
          for (int r = 0; r < 4; ++r) oA[nd][r] *= alo[r];
#pragma unroll
        for (int r = 0; r < 4; ++r) lsA[r] *= alo[r];
      }
#pragma unroll
      for (int kf = 0; kf < 4; ++kf)
#pragma unroll
        for (int r = 0; r < 4; ++r)
          sA[kf][r] = __builtin_amdgcn_exp2f(fmaf(sA[kf][r], c1, -mA));
      // Ps reuse: same-wave DS ordering + compiler lgkm waits make this safe
#pragma unroll
      for (int kf = 0; kf < 4; ++kf) {
        u32 w0 = (u32)f2b(sA[kf][0]) | ((u32)f2b(sA[kf][1]) << 16);
        u32 w1 = (u32)f2b(sA[kf][2]) | ((u32)f2b(sA[kf][3]) << 16);
        *(u64*)(pw + lo * 128 + ((kf * 32 + hi * 8) ^ swl)) = (u64)w0 | ((u64)w1 << 32);
      }
      bf16x8 pa[2];
#pragma unroll
      for (int ks = 0; ks < 2; ++ks)
        pa[ks] = ldf(pw + lo * 128 + ((ks * 64 + hi * 16) ^ swl));
      __builtin_amdgcn_s_setprio(1);
#pragma unroll
      for (int ks = 0; ks < 2; ++ks) {
#pragma unroll
        for (int nd = 0; nd < 4; ++nd) oA[nd] = MFMA16(pa[ks], vb[nd][ks], oA[nd]);
        lsA = MFMA16(pa[ks], onesv, lsA);
      }
      __builtin_amdgcn_s_setprio(0);
    }

    __builtin_amdgcn_sched_barrier(0);
    __builtin_amdgcn_s_barrier();  // all reads of cur done before re-stage
  }

  // ---- epilogues: y[b][t][h*64+d] bf16 (O rows (hi,r), col lo)
#pragma unroll
  for (int s = 0; s < 2; ++s) {
    const int q0 = s ? q0B : q0A;
    f32x4* o = s ? oB : oA;
    f32x4 ls = s ? lsB : lsA;
    f32x4 inv;
#pragma unroll
    for (int r = 0; r < 4; ++r) inv[r] = 1.0f / ls[r];
#pragma unroll
    for (int nd = 0; nd < 4; ++nd)
#pragma unroll
      for (int r = 0; r < 4; ++r) {
        int t = q0 + hi * 4 + r;
        int d = nd * 16 + lo;
        Y[((size_t)b * 1024 + t) * 768 + h * 64 + d] = f2b(o[nd][r] * inv[r]);
      }
  }
}

// ---------------- launcher ----------------
extern "C" void kernel_launch(void* const* d_in, const int* in_sizes, int n_in,
                              void* d_out, int out_size, void* d_ws, size_t ws_size,
                              hipStream_t stream) {
  const float* x  = (const float*)d_in[0];
  const float* Wa = (const float*)d_in[1];
  const float* ba = (const float*)d_in[2];
  const float* Wp = (const float*)d_in[3];
  const float* bp = (const float*)d_in[4];
  float* out = (float*)d_out;
  char* ws = (char*)d_ws;

  constexpr size_t XB  = 0;                       // x bf16   [8192][768]
  constexpr size_t WAB = 12582912;                // W_attn bf16 [2304][768]
  constexpr size_t WPB = WAB + 3538944;           // W_proj bf16 [768][768]
  constexpr size_t QS  = WPB + 1179648;           // q bf16 [96][1024][64]
  constexpr size_t KS  = QS + 12582912;           // k bf16 [96][1024][64]
  constexpr size_t VTS = KS + 12582912;           // v^T bf16 [96][64][1024]
  constexpr size_t YB  = VTS + 12582912;          // y bf16 [8192][768]

  u16* xb  = (u16*)(ws + XB);
  u16* wab = (u16*)(ws + WAB);
  u16* wpb = (u16*)(ws + WPB);
  u16* qs  = (u16*)(ws + QS);
  u16* ks  = (u16*)(ws + KS);
  u16* vts = (u16*)(ws + VTS);
  u16* yb  = (u16*)(ws + YB);

  cvt3_kernel<<<2048, 256, 0, stream>>>(
      (const float4*)x,  (ushort4*)xb,  8192 * 768 / 4,
      (const float4*)Wa, (ushort4*)wab, 2304 * 768 / 4,
      (const float4*)Wp, (ushort4*)wpb, 768 * 768 / 4);

  gemm4<128, 0><<<dim3(12, 64), 256, 0, stream>>>(xb, wab, ba, 8192, 2304, 768,
                                                  qs, ks, vts, nullptr);
  attn_kernel<<<dim3(8, 96), 256, 0, stream>>>(qs, ks, vts, yb);
  gemm4<64, 1><<<dim3(4, 128), 256, 0, stream>>>(yb, wpb, bp, 8192, 768, 768,
                                                 nullptr, nullptr, nullptr, out);
}

// Round 12
// 96.158 us; speedup vs baseline: 1.0367x; 1.0367x over previous
//
#include <hip/hip_runtime.h>

typedef unsigned short u16;
typedef unsigned int u32;
typedef unsigned long long u64;
typedef __attribute__((ext_vector_type(8))) __bf16 bf16x8;
typedef __attribute__((ext_vector_type(4))) float f32x4;
typedef __attribute__((ext_vector_type(4))) int i32x4;

#define MFMA16(a, b, c) __builtin_amdgcn_mfma_f32_16x16x32_bf16(a, b, c, 0, 0, 0)

__device__ __forceinline__ u16 f2b(float f) {
  __bf16 h = (__bf16)f;
  return __builtin_bit_cast(u16, h);
}

__device__ __forceinline__ float mx3(float a, float b, float c) {
  return fmaxf(fmaxf(a, b), c);  // clang fuses to v_max3_f32
}

// global -> LDS direct (wave-uniform LDS base + lane*16; global addr per-lane)
__device__ __forceinline__ void gl_lds16(const void* g, void* l) {
  __builtin_amdgcn_global_load_lds(
      (const __attribute__((address_space(1))) void*)g,
      (__attribute__((address_space(3))) void*)l, 16, 0, 0);
}

__device__ __forceinline__ bf16x8 ldf(const void* p) {
  return __builtin_bit_cast(bf16x8, *(const i32x4*)p);
}

// ---------------- fused f32 -> bf16 convert (one launch) ----------------
__global__ __launch_bounds__(256) void cvt3_kernel(
    const float4* __restrict__ a, ushort4* __restrict__ oa, int na4,
    const float4* __restrict__ b, ushort4* __restrict__ ob, int nb4,
    const float4* __restrict__ c, ushort4* __restrict__ oc, int nc4) {
  const int step = gridDim.x * blockDim.x;
  const int t0 = blockIdx.x * blockDim.x + threadIdx.x;
  for (int i = t0; i < na4; i += step) {
    float4 v = a[i];
    ushort4 o; o.x = f2b(v.x); o.y = f2b(v.y); o.z = f2b(v.z); o.w = f2b(v.w);
    oa[i] = o;
  }
  for (int i = t0; i < nb4; i += step) {
    float4 v = b[i];
    ushort4 o; o.x = f2b(v.x); o.y = f2b(v.y); o.z = f2b(v.z); o.w = f2b(v.w);
    ob[i] = o;
  }
  for (int i = t0; i < nc4; i += step) {
    float4 v = c[i];
    ushort4 o; o.x = f2b(v.x); o.y = f2b(v.y); o.z = f2b(v.z); o.w = f2b(v.w);
    oc[i] = o;
  }
}

// ---------------- GEMM v4 (unchanged from round 8) ----------------
template <int BM, int EPI>
__global__ __launch_bounds__(256, 3) void gemm4(
    const u16* __restrict__ A, const u16* __restrict__ B,
    const float* __restrict__ bias, int M, int N, int K,
    u16* __restrict__ q_s, u16* __restrict__ k_s, u16* __restrict__ vt_s,
    float* __restrict__ outf) {
  constexpr int BN = 192;
  constexpr int MR = BM / 32;
  constexpr int NR = 6;
  constexpr int IA = BM / 32;
  constexpr int IB = 6;
  __shared__ __align__(16) u16 As[BM * 64];
  __shared__ __align__(16) u16 Bs[BN * 64];
  const int tid = threadIdx.x;
  const int w = tid >> 6, l = tid & 63;
  const int lo = l & 15, hi = l >> 4;
  const int wr = w >> 1, wc = w & 1;
  const int nwg = gridDim.x * gridDim.y;
  int bid = blockIdx.y * gridDim.x + blockIdx.x;
  bid = (bid & 7) * (nwg >> 3) + (bid >> 3);
  const int bm0 = (bid / gridDim.x) * BM;
  const int bn0 = (bid % gridDim.x) * BN;
  const size_t Kb = (size_t)K * 2;
  const char* Ab = (const char*)A;
  const char* Bb = (const char*)B;
  const int lrow8 = l >> 3;
  const int lcol = (l & 7) * 16;

  f32x4 acc[MR][NR] = {};

  for (int kt = 0; kt < K; kt += 64) {
    __syncthreads();
#pragma unroll
    for (int i = 0; i < IA; ++i) {
      int rl = (w * IA + i) * 8 + lrow8;
      int cb = lcol ^ ((rl & 7) << 4);
      gl_lds16(Ab + (size_t)(bm0 + rl) * Kb + kt * 2 + cb,
               (char*)As + (w * IA + i) * 1024);
    }
#pragma unroll
    for (int i = 0; i < IB; ++i) {
      int rl = (w * IB + i) * 8 + lrow8;
      int cb = lcol ^ ((rl & 7) << 4);
      gl_lds16(Bb + (size_t)(bn0 + rl) * Kb + kt * 2 + cb,
               (char*)Bs + (w * IB + i) * 1024);
    }
    __syncthreads();
#pragma unroll
    for (int ks = 0; ks < 2; ++ks) {
      bf16x8 bfr[NR];
#pragma unroll
      for (int nf = 0; nf < NR; ++nf) {
        int r = wc * 96 + nf * 16 + lo;
        bfr[nf] = ldf((char*)Bs + r * 128 + ((ks * 64 + hi * 16) ^ ((r & 7) << 4)));
      }
#pragma unroll
      for (int mf = 0; mf < MR; ++mf) {
        int r = wr * (MR * 16) + mf * 16 + lo;
        bf16x8 afr = ldf((char*)As + r * 128 + ((ks * 64 + hi * 16) ^ ((r & 7) << 4)));
#pragma unroll
        for (int nf = 0; nf < NR; ++nf) acc[mf][nf] = MFMA16(afr, bfr[nf], acc[mf][nf]);
      }
    }
  }

#pragma unroll
  for (int nf = 0; nf < NR; ++nf) {
    int col = bn0 + wc * 96 + nf * 16 + lo;
    float bv = bias[col];
    if (EPI == 0) {
      int seg = col / 768;
      int cs = col - seg * 768;
      int h = cs >> 6, d = cs & 63;
      u16* dst = (seg == 0) ? q_s : k_s;
#pragma unroll
      for (int mf = 0; mf < MR; ++mf) {
        int m0 = bm0 + wr * (MR * 16) + mf * 16 + hi * 4;
        int bb = m0 >> 10, t0 = m0 & 1023;
        size_t bh = (size_t)(bb * 12 + h);
        if (seg < 2) {
#pragma unroll
          for (int r = 0; r < 4; ++r)
            dst[(bh * 1024 + t0 + r) * 64 + d] = f2b(acc[mf][nf][r] + bv);
        } else {
          ushort4 pk;
          pk.x = f2b(acc[mf][nf][0] + bv);
          pk.y = f2b(acc[mf][nf][1] + bv);
          pk.z = f2b(acc[mf][nf][2] + bv);
          pk.w = f2b(acc[mf][nf][3] + bv);
          *(ushort4*)&vt_s[(bh * 64 + d) * 1024 + t0] = pk;
        }
      }
    } else {
#pragma unroll
      for (int mf = 0; mf < MR; ++mf) {
        int m0 = bm0 + wr * (MR * 16) + mf * 16 + hi * 4;
#pragma unroll
        for (int r = 0; r < 4; ++r) outf[(size_t)(m0 + r) * N + col] = acc[mf][nf][r] + bv;
      }
    }
  }
}

// ---------------- causal flash attention, v9 ----------------
// = round-10 v7 (best) with ONE structural change: single barrier per
// iteration. v7 issued STAGE(cur^1) BEFORE the top barrier, racing prior
// readers of cur^1 -> needed a bottom barrier. v9 issues STAGE AFTER the
// top barrier: it then happens-after all waves' compute(kt-1) by program
// order, so the double buffer is overwrite-safe with one barrier. The only
// outstanding VMEM at the wait is the 4 own-wave stage loads -> vmcnt(0)
// exact. One inter-segment barrier protects re-staging buf 0.
// Plus: max3-shaped fmax tree (T17). Everything else identical to v7.
__global__ __launch_bounds__(256) void attn_kernel(
    const u16* __restrict__ Q, const u16* __restrict__ Kg,
    const u16* __restrict__ Vt, u16* __restrict__ Y) {
  __shared__ __align__(16) u16 Ks[2][64 * 64];
  __shared__ __align__(16) u16 Vs[2][64 * 64];
  __shared__ __align__(16) u16 Ps[4][16 * 64];
  const int tid = threadIdx.x;
  const int w = tid >> 6, l = tid & 63;
  const int lo = l & 15, hi = l >> 4;
  // XCD-aware bijective remap (768 blocks % 8 == 0)
  int bid = blockIdx.y * gridDim.x + blockIdx.x;
  bid = (bid & 7) * 96 + (bid >> 3);
  const int bh = bid >> 3;
  const int pr = bid & 7;  // 0..7 -> tiles {pr, 15-pr}
  const int b = bh / 12, h = bh % 12;
  const float c1 = 0.125f * 1.44269504f;  // scale * log2(e)
  char* pw = (char*)&Ps[w][0];
  const int swl = (lo & 7) << 4;
  const u16* Qb = Q + (size_t)bh * 65536;
  const char* Kbp = (const char*)(Kg + (size_t)bh * 65536);
  const char* Vbp = (const char*)(Vt + (size_t)bh * 65536);  // [64 d][1024 t]

  bf16x8 onesv;
#pragma unroll
  for (int j = 0; j < 8; ++j) onesv[j] = (__bf16)1.0f;

  auto STAGE = [&](int buf, int kb) {
#pragma unroll
    for (int i = 0; i < 2; ++i) {
      int c = w * 2 + i;
      int row = c * 8 + (l >> 3);                    // 8 rows (128B) / chunk
      int cb = ((l & 7) * 16) ^ ((row & 7) << 4);    // inverse-swizzled source
      gl_lds16(Kbp + (size_t)(kb + row) * 128 + cb, (char*)&Ks[buf][0] + c * 1024);
      gl_lds16(Vbp + (size_t)row * 2048 + (size_t)kb * 2 + cb, (char*)&Vs[buf][0] + c * 1024);
    }
  };

  for (int sg = 0; sg < 2; ++sg) {
    const int tile = sg ? (15 - pr) : pr;
    const int q0 = tile * 64 + w * 16;  // wave's 16 q-rows
    const int nt = tile + 1;            // KV tiles of 64
    const int qr = q0 + lo;             // this lane's P-row

    bf16x8 qf[2];
#pragma unroll
    for (int ks = 0; ks < 2; ++ks)
      qf[ks] = ldf(Qb + (size_t)(q0 + lo) * 64 + ks * 32 + hi * 8);

    f32x4 o[4] = {};
    f32x4 lsum = {0.f, 0.f, 0.f, 0.f};
    float mrow = -1e30f;

    __builtin_amdgcn_s_barrier();  // prior segment's readers done before re-stage
    STAGE(0, 0);
    for (int kt = 0; kt < nt; ++kt) {
      const int cur = kt & 1;
      // stage(kt) is the only outstanding VMEM here -> exact wait
      asm volatile("s_waitcnt vmcnt(0)" ::: "memory");
      __builtin_amdgcn_s_barrier();  // all waves' chunks of stage(kt) visible
      __builtin_amdgcn_sched_barrier(0);
      // Issue next stage AFTER the barrier: happens-after all waves'
      // compute(kt-1) (the prior readers of cur^1) by program order.
      if (kt + 1 < nt) STAGE(cur ^ 1, (kt + 1) * 64);
      const char* Kt = (const char*)&Ks[cur][0];
      const char* Vv = (const char*)&Vs[cur][0];
      const int kb = kt * 64;

      // ---- swapped QK^T: st[kf] = D[k][q]; lane holds q=lo, k=kf*16+hi*4+r
      f32x4 st[4] = {};
      __builtin_amdgcn_s_setprio(1);
#pragma unroll
      for (int kf = 0; kf < 4; ++kf) {
        int rb = (kf * 16 + lo) * 128;
#pragma unroll
        for (int ks = 0; ks < 2; ++ks)
          st[kf] = MFMA16(ldf(Kt + rb + ((ks * 64 + hi * 16) ^ swl)), qf[ks], st[kf]);
      }
      __builtin_amdgcn_s_setprio(0);
      // ---- V frags (lgkm latency hides under softmax VALU)
      bf16x8 vb[4][2];
#pragma unroll
      for (int nd = 0; nd < 4; ++nd) {
        int rb = (nd * 16 + lo) * 128;
#pragma unroll
        for (int ks = 0; ks < 2; ++ks)
          vb[nd][ks] = ldf(Vv + rb + ((ks * 64 + hi * 16) ^ swl));
      }
      // ---- causal mask (only diagonal tile crosses; swapped indices)
      if (kt == nt - 1) {
#pragma unroll
        for (int kf = 0; kf < 4; ++kf)
#pragma unroll
          for (int r = 0; r < 4; ++r) {
            int kcol = kb + kf * 16 + hi * 4 + r;
            if (kcol > qr) st[kf][r] = -1e30f;
          }
      }
      // ---- online softmax; row q=lo spread over 4 hi-lanes (max3 tree, T17)
      float t0 = mx3(st[0][0], st[0][1], st[0][2]);
      float t1 = mx3(st[0][3], st[1][0], st[1][1]);
      float t2 = mx3(st[1][2], st[1][3], st[2][0]);
      float t3 = mx3(st[2][1], st[2][2], st[2][3]);
      float t4 = mx3(st[3][0], st[3][1], st[3][2]);
      float lm = fmaxf(mx3(t0, t1, t2), mx3(t3, t4, st[3][3]));
      if (__any(lm * c1 > mrow + 8.0f)) {  // defer-max (T13), lane-local check
        float LM = fmaxf(lm, __shfl_xor(lm, 16));
        LM = fmaxf(LM, __shfl_xor(LM, 32));
        float Mn = fmaxf(mrow, LM * c1);
        float alP = __builtin_amdgcn_exp2f(mrow - Mn);
        mrow = Mn;
        f32x4 alo;  // broadcast P-domain alpha (row=lo) -> O-domain rows (hi,r)
#pragma unroll
        for (int r = 0; r < 4; ++r) alo[r] = __shfl(alP, hi * 4 + r);
#pragma unroll
        for (int nd = 0; nd < 4; ++nd)
#pragma unroll
          for (int r = 0; r < 4; ++r) o[nd][r] *= alo[r];
#pragma unroll
        for (int r = 0; r < 4; ++r) lsum[r] *= alo[r];
      }
#pragma unroll
      for (int kf = 0; kf < 4; ++kf)
#pragma unroll
        for (int r = 0; r < 4; ++r)
          st[kf][r] = __builtin_amdgcn_exp2f(fmaf(st[kf][r], c1, -mrow));
      // ---- P -> LDS, PACKED: lane owns row lo, k-chunk kf*16+hi*4..+3
      // (8B contiguous). Same XOR involution as the read (swl = (lo&7)<<4).
#pragma unroll
      for (int kf = 0; kf < 4; ++kf) {
        u32 w0 = (u32)f2b(st[kf][0]) | ((u32)f2b(st[kf][1]) << 16);
        u32 w1 = (u32)f2b(st[kf][2]) | ((u32)f2b(st[kf][3]) << 16);
        *(u64*)(pw + lo * 128 + ((kf * 32 + hi * 8) ^ swl)) =
            (u64)w0 | ((u64)w1 << 32);
      }
      bf16x8 pa[2];
#pragma unroll
      for (int ks = 0; ks < 2; ++ks)
        pa[ks] = ldf(pw + lo * 128 + ((ks * 64 + hi * 16) ^ swl));
      // ---- PV: O += P V ; rowsum l += P . 1 (ones-MFMA)
      __builtin_amdgcn_s_setprio(1);
#pragma unroll
      for (int ks = 0; ks < 2; ++ks) {
#pragma unroll
        for (int nd = 0; nd < 4; ++nd) o[nd] = MFMA16(pa[ks], vb[nd][ks], o[nd]);
        lsum = MFMA16(pa[ks], onesv, lsum);
      }
      __builtin_amdgcn_s_setprio(0);
      __builtin_amdgcn_sched_barrier(0);
    }

    // ---- epilogue: y[b][t][h*64+d] bf16 (O rows (hi,r), col lo)
    f32x4 inv;
#pragma unroll
    for (int r = 0; r < 4; ++r) inv[r] = 1.0f / lsum[r];
#pragma unroll
    for (int nd = 0; nd < 4; ++nd)
#pragma unroll
      for (int r = 0; r < 4; ++r) {
        int t = q0 + hi * 4 + r;
        int d = nd * 16 + lo;
        Y[((size_t)b * 1024 + t) * 768 + h * 64 + d] = f2b(o[nd][r] * inv[r]);
      }
  }
}

// ---------------- launcher ----------------
extern "C" void kernel_launch(void* const* d_in, const int* in_sizes, int n_in,
                              void* d_out, int out_size, void* d_ws, size_t ws_size,
                              hipStream_t stream) {
  const float* x  = (const float*)d_in[0];
  const float* Wa = (const float*)d_in[1];
  const float* ba = (const float*)d_in[2];
  const float* Wp = (const float*)d_in[3];
  const float* bp = (const float*)d_in[4];
  float* out = (float*)d_out;
  char* ws = (char*)d_ws;

  constexpr size_t XB  = 0;                       // x bf16   [8192][768]
  constexpr size_t WAB = 12582912;                // W_attn bf16 [2304][768]
  constexpr size_t WPB = WAB + 3538944;           // W_proj bf16 [768][768]
  constexpr size_t QS  = WPB + 1179648;           // q bf16 [96][1024][64]
  constexpr size_t KS  = QS + 12582912;           // k bf16 [96][1024][64]
  constexpr size_t VTS = KS + 12582912;           // v^T bf16 [96][64][1024]
  constexpr size_t YB  = VTS + 12582912;          // y bf16 [8192][768]

  u16* xb  = (u16*)(ws + XB);
  u16* wab = (u16*)(ws + WAB);
  u16* wpb = (u16*)(ws + WPB);
  u16* qs  = (u16*)(ws + QS);
  u16* ks  = (u16*)(ws + KS);
  u16* vts = (u16*)(ws + VTS);
  u16* yb  = (u16*)(ws + YB);

  cvt3_kernel<<<2048, 256, 0, stream>>>(
      (const float4*)x,  (ushort4*)xb,  8192 * 768 / 4,
      (const float4*)Wa, (ushort4*)wab, 2304 * 768 / 4,
      (const float4*)Wp, (ushort4*)wpb, 768 * 768 / 4);

  gemm4<128, 0><<<dim3(12, 64), 256, 0, stream>>>(xb, wab, ba, 8192, 2304, 768,
                                                  qs, ks, vts, nullptr);
  attn_kernel<<<dim3(8, 96), 256, 0, stream>>>(qs, ks, vts, yb);
  gemm4<64, 1><<<dim3(4, 128), 256, 0, stream>>>(yb, wpb, bp, 8192, 768, 768,
                                                 nullptr, nullptr, nullptr, out);
}